// Round 1
// baseline (697.421 us; speedup 1.0000x reference)
//
#include <hip/hip_runtime.h>
#include <hip/hip_bf16.h>

// Problem constants (match reference setup_inputs)
#define H_DIM   4096   // input features (K of the GEMM)
#define M_DIM   4096   // output features (N of the GEMM, W rows)
#define N_ROWS  8192   // B*S flattened x rows (M of the GEMM)
#define NNZ_ROW 2048   // fixed 50% density per row

typedef __bf16 bf16x8 __attribute__((ext_vector_type(8)));
typedef float  f32x4  __attribute__((ext_vector_type(4)));

// fp32 -> bf16 round-to-nearest-even on raw bits (inputs are finite/normal)
__device__ __forceinline__ unsigned short f2bf(float f) {
    unsigned int u = __float_as_uint(f);
    u += 0x7fffu + ((u >> 16) & 1u);
    return (unsigned short)(u >> 16);
}

// async global->LDS, 16B per lane. LDS dest is wave-uniform base + lane*16,
// which our thread-linear layout satisfies exactly.
__device__ __forceinline__ void gld_lds16(const void* g, void* l) {
    __builtin_amdgcn_global_load_lds(
        (__attribute__((address_space(1))) const void*)g,
        (__attribute__((address_space(3))) void*)l,
        16, 0, 0);
}

// ---------------------------------------------------------------------------
// Kernel 1: decode CSR row -> dense bf16 row via LDS staging.
// One block (256 thr) per W row: zero 8KB LDS, scatter 2048 values, store
// coalesced 16B chunks. Global writes fully coalesced, no pre-memset needed.
// ---------------------------------------------------------------------------
__global__ __launch_bounds__(256) void decode_w_kernel(
        const float* __restrict__ values,
        const int*   __restrict__ col_idx,
        unsigned short* __restrict__ W) {
    __shared__ unsigned short rowbuf[H_DIM];     // 8 KiB
    const int m = blockIdx.x;
    const int t = threadIdx.x;

    uint4 z = make_uint4(0u, 0u, 0u, 0u);
    ((uint4*)rowbuf)[t]       = z;
    ((uint4*)rowbuf)[t + 256] = z;
    __syncthreads();

    const long base = (long)m * NNZ_ROW;
    #pragma unroll
    for (int j = 0; j < NNZ_ROW; j += 256) {
        float v = values[base + j + t];
        int   c = col_idx[base + j + t];
        rowbuf[c] = f2bf(v);
    }
    __syncthreads();

    uint4* out = (uint4*)(W + (long)m * H_DIM);
    out[t]       = ((uint4*)rowbuf)[t];
    out[t + 256] = ((uint4*)rowbuf)[t + 256];
}

// ---------------------------------------------------------------------------
// Kernel 2: x fp32 -> bf16, 8 elements/thread, 16B stores.
// ---------------------------------------------------------------------------
__global__ __launch_bounds__(256) void convert_x_kernel(
        const float4* __restrict__ x, uint4* __restrict__ xb) {
    const long i = blockIdx.x * 256L + threadIdx.x;
    float4 a = x[2 * i];
    float4 b = x[2 * i + 1];
    union { unsigned short s[8]; uint4 v; } r;
    r.s[0] = f2bf(a.x); r.s[1] = f2bf(a.y); r.s[2] = f2bf(a.z); r.s[3] = f2bf(a.w);
    r.s[4] = f2bf(b.x); r.s[5] = f2bf(b.y); r.s[6] = f2bf(b.z); r.s[7] = f2bf(b.w);
    xb[i] = r.v;
}

// ---------------------------------------------------------------------------
// Kernel 3: C[N_ROWS, M_DIM] = A[N_ROWS, K] @ B[M_DIM, K]^T, bf16 in fp32 out.
// m97 structure: 128x128 block tile, BK=32, 4 waves (2x2), each wave 64x64 as
// 4x4 grid of 16x16x32 MFMAs. global_load_lds width=16 staging, 2 barriers/K.
// ---------------------------------------------------------------------------
__global__ __launch_bounds__(256) void gemm_bt_kernel(
        const unsigned short* __restrict__ A,   // [N_ROWS][H_DIM] bf16
        const unsigned short* __restrict__ B,   // [M_DIM][H_DIM]  bf16
        float* __restrict__ C) {                // [N_ROWS][M_DIM] fp32
    __shared__ unsigned short As[128 * 32];     // 8 KiB
    __shared__ unsigned short Bs[128 * 32];     // 8 KiB

    const int t    = threadIdx.x;
    const int lane = t & 63;
    const int wid  = t >> 6;
    const int wm   = wid >> 1;   // 0..1: wave row
    const int wn   = wid & 1;    // 0..1: wave col

    const long row0 = (long)blockIdx.x * 128;   // A rows
    const long col0 = (long)blockIdx.y * 128;   // B rows (= C cols)

    // staging: thread t copies 8 contiguous bf16 (16B); 2 chunks per matrix
    const int sr = t >> 2;          // tile row 0..63 for chunk 0
    const int sc = (t & 3) * 8;     // tile col {0,8,16,24}
    const unsigned short* Ag0 = A + (row0 + sr) * H_DIM + sc;
    const unsigned short* Ag1 = Ag0 + 64L * H_DIM;
    const unsigned short* Bg0 = B + (col0 + sr) * H_DIM + sc;
    const unsigned short* Bg1 = Bg0 + 64L * H_DIM;
    unsigned short* Al0 = &As[t * 8];
    unsigned short* Al1 = &As[2048 + t * 8];
    unsigned short* Bl0 = &Bs[t * 8];
    unsigned short* Bl1 = &Bs[2048 + t * 8];

    f32x4 acc[4][4];
    #pragma unroll
    for (int i = 0; i < 4; ++i)
        #pragma unroll
        for (int j = 0; j < 4; ++j)
            acc[i][j] = (f32x4)0.0f;

    // fragment read base: A[m=lane&15][k=(lane>>4)*8 + j]
    const int fr = lane & 15;
    const int fk = (lane >> 4) * 8;
    const unsigned short* Ard = &As[(wm * 64 + fr) * 32 + fk];
    const unsigned short* Brd = &Bs[(wn * 64 + fr) * 32 + fk];

    for (int k0 = 0; k0 < H_DIM; k0 += 32) {
        __syncthreads();                      // LDS consumed from prev iter
        gld_lds16(Ag0 + k0, Al0);
        gld_lds16(Ag1 + k0, Al1);
        gld_lds16(Bg0 + k0, Bl0);
        gld_lds16(Bg1 + k0, Bl1);
        __syncthreads();                      // vmcnt(0) drain before barrier

        bf16x8 a[4], b[4];
        #pragma unroll
        for (int i = 0; i < 4; ++i) a[i] = *(const bf16x8*)(Ard + i * 16 * 32);
        #pragma unroll
        for (int j = 0; j < 4; ++j) b[j] = *(const bf16x8*)(Brd + j * 16 * 32);

        #pragma unroll
        for (int i = 0; i < 4; ++i)
            #pragma unroll
            for (int j = 0; j < 4; ++j)
                acc[i][j] = __builtin_amdgcn_mfma_f32_16x16x32_bf16(
                                a[i], b[j], acc[i][j], 0, 0, 0);
    }

    // epilogue: D col = lane&15, row = (lane>>4)*4 + reg  [m89/m91 verified]
    const int dcol = lane & 15;
    const int drow = (lane >> 4) * 4;
    #pragma unroll
    for (int i = 0; i < 4; ++i) {
        const long r = row0 + wm * 64 + i * 16 + drow;
        #pragma unroll
        for (int j = 0; j < 4; ++j) {
            float* cp = C + r * M_DIM + (col0 + wn * 64 + j * 16 + dcol);
            #pragma unroll
            for (int q = 0; q < 4; ++q)
                cp[q * (long)M_DIM] = acc[i][j][q];
        }
    }
}

// ---------------------------------------------------------------------------
// Fallback (only if d_ws can't hold W+Xb): naive fp32 sparse dot per output.
// Correct but slow; presence lets us detect insufficient ws from dur_us.
// ---------------------------------------------------------------------------
__global__ __launch_bounds__(256) void naive_kernel(
        const float* __restrict__ x, const float* __restrict__ vals,
        const int* __restrict__ cols, float* __restrict__ out) {
    const long idx = blockIdx.x * 256L + threadIdx.x;
    const int  m   = (int)(idx & (M_DIM - 1));
    const long n   = idx >> 12;
    const float* xr = x + n * H_DIM;
    const float* v  = vals + (long)m * NNZ_ROW;
    const int*   c  = cols + (long)m * NNZ_ROW;
    float s = 0.f;
    for (int j = 0; j < NNZ_ROW; ++j) s += v[j] * xr[c[j]];
    out[idx] = s;
}

extern "C" void kernel_launch(void* const* d_in, const int* in_sizes, int n_in,
                              void* d_out, int out_size, void* d_ws, size_t ws_size,
                              hipStream_t stream) {
    const float* x       = (const float*)d_in[0];
    const float* values  = (const float*)d_in[1];
    const int*   col_idx = (const int*)d_in[2];
    float* out = (float*)d_out;

    const size_t wbytes = (size_t)M_DIM * H_DIM * sizeof(unsigned short);   // 33.5 MB
    const size_t xbytes = (size_t)N_ROWS * H_DIM * sizeof(unsigned short);  // 67 MB

    if (ws_size >= wbytes + xbytes) {
        unsigned short* W  = (unsigned short*)d_ws;
        unsigned short* Xb = (unsigned short*)((char*)d_ws + wbytes);

        decode_w_kernel<<<M_DIM, 256, 0, stream>>>(values, col_idx, W);

        const long xvec = (long)N_ROWS * H_DIM / 8;   // 8 floats per thread
        convert_x_kernel<<<(int)(xvec / 256), 256, 0, stream>>>(
            (const float4*)x, (uint4*)Xb);

        dim3 grid(N_ROWS / 128, M_DIM / 128);         // 64 x 32
        gemm_bt_kernel<<<grid, 256, 0, stream>>>(Xb, W, out);
    } else {
        naive_kernel<<<(int)((long)N_ROWS * M_DIM / 256), 256, 0, stream>>>(
            x, values, col_idx, out);
    }
}